// Round 1
// baseline (1738.403 us; speedup 1.0000x reference)
//
#include <hip/hip_runtime.h>
#include <math.h>

#define NN 100000      // nodes
#define NE 1000000     // edges (without self loops)
#define NETOT 1100000  // edges + self loops
#define HD 64          // hidden / feature dim
#define NG 128         // graphs
#define NEG_SLOPE 0.2f

// h = xe @ W ; alpha_s = h . a_src ; alpha_d = h . a_dst
// xe = apply_relu ? relu(inp + bias_prev) : inp
__global__ __launch_bounds__(256) void k_transform(
    const float* __restrict__ inp, const float* __restrict__ bias_prev,
    const float* __restrict__ W, const float* __restrict__ a_src,
    const float* __restrict__ a_dst, float* __restrict__ h,
    float* __restrict__ alpha_s, float* __restrict__ alpha_d, int apply_relu)
{
    __shared__ float sx[256];
    int node = (blockIdx.x * 256 + threadIdx.x) >> 6;
    int lane = threadIdx.x & 63;
    float xe = inp[(size_t)node * HD + lane];
    if (apply_relu) {
        xe += bias_prev[lane];
        xe = xe > 0.f ? xe : 0.f;
    }
    sx[threadIdx.x] = xe;
    __syncthreads();
    const float* sxw = sx + (threadIdx.x & 192);   // this wave's row of 64
    float hj = 0.f;
    #pragma unroll
    for (int k4 = 0; k4 < 16; ++k4) {
        float4 xv = reinterpret_cast<const float4*>(sxw)[k4];
        int kb = k4 * 4;
        hj = fmaf(xv.x, W[(kb + 0) * HD + lane], hj);
        hj = fmaf(xv.y, W[(kb + 1) * HD + lane], hj);
        hj = fmaf(xv.z, W[(kb + 2) * HD + lane], hj);
        hj = fmaf(xv.w, W[(kb + 3) * HD + lane], hj);
    }
    h[(size_t)node * HD + lane] = hj;
    float s = hj * a_src[lane];
    float d = hj * a_dst[lane];
    #pragma unroll
    for (int off = 32; off > 0; off >>= 1) {
        s += __shfl_xor(s, off, 64);
        d += __shfl_xor(d, off, 64);
    }
    if (lane == 0) { alpha_s[node] = s; alpha_d[node] = d; }
}

// denom[dst] += exp(leaky_relu(alpha_s[src] + alpha_d[dst]))
__global__ __launch_bounds__(256) void k_edge_denom(
    const int* __restrict__ esrc, const int* __restrict__ edst,
    const float* __restrict__ alpha_s, const float* __restrict__ alpha_d,
    float* __restrict__ denom)
{
    int e = blockIdx.x * 256 + threadIdx.x;
    if (e >= NETOT) return;
    int s, d;
    if (e < NE) { s = esrc[e]; d = edst[e]; } else { s = e - NE; d = s; }
    float ev = alpha_s[s] + alpha_d[d];
    ev = ev > 0.f ? ev : NEG_SLOPE * ev;
    atomicAdd(&denom[d], expf(ev));
}

// hout[dst] += (exp(e)/denom[dst]) * h[src]   (one wave per edge, lane = channel)
__global__ __launch_bounds__(256) void k_edge_aggr(
    const int* __restrict__ esrc, const int* __restrict__ edst,
    const float* __restrict__ alpha_s, const float* __restrict__ alpha_d,
    const float* __restrict__ denom, const float* __restrict__ h,
    float* __restrict__ hout)
{
    int wid = (blockIdx.x * 256 + threadIdx.x) >> 6;
    int lane = threadIdx.x & 63;
    int s, d;
    if (wid < NE) { s = esrc[wid]; d = edst[wid]; } else { s = wid - NE; d = s; }
    float ev = alpha_s[s] + alpha_d[d];
    ev = ev > 0.f ? ev : NEG_SLOPE * ev;
    float coef = expf(ev) / denom[d];
    atomicAdd(&hout[(size_t)d * HD + lane], coef * h[(size_t)s * HD + lane]);
}

// gate score per node + per-graph exp-sum
__global__ __launch_bounds__(256) void k_gate(
    const float* __restrict__ hraw2, const float* __restrict__ b2,
    const float* __restrict__ gate_w, const float* __restrict__ gate_b,
    const int* __restrict__ batch, float* __restrict__ gvals,
    float* __restrict__ gden)
{
    int node = (blockIdx.x * 256 + threadIdx.x) >> 6;
    int lane = threadIdx.x & 63;
    float h3 = hraw2[(size_t)node * HD + lane] + b2[lane];
    float s = h3 * gate_w[lane];
    #pragma unroll
    for (int off = 32; off > 0; off >>= 1) s += __shfl_xor(s, off, 64);
    float g = s + gate_b[0];
    if (lane == 0) {
        gvals[node] = g;
        atomicAdd(&gden[batch[node]], expf(g));
    }
}

// pooled[graph] += coef * h3
__global__ __launch_bounds__(256) void k_pool(
    const float* __restrict__ hraw2, const float* __restrict__ b2,
    const float* __restrict__ gvals, const float* __restrict__ gden,
    const int* __restrict__ batch, float* __restrict__ pooled)
{
    int node = (blockIdx.x * 256 + threadIdx.x) >> 6;
    int lane = threadIdx.x & 63;
    int b = batch[node];
    float coef = expf(gvals[node]) / gden[b];
    float h3 = hraw2[(size_t)node * HD + lane] + b2[lane];
    atomicAdd(&pooled[b * HD + lane], coef * h3);
}

// out = pooled @ lin_w + lin_b   (128 x 64 x 64)
__global__ __launch_bounds__(256) void k_final(
    const float* __restrict__ pooled, const float* __restrict__ lin_w,
    const float* __restrict__ lin_b, float* __restrict__ out)
{
    __shared__ float sp[256];
    int row = (blockIdx.x * 256 + threadIdx.x) >> 6;  // graph id
    int lane = threadIdx.x & 63;
    sp[threadIdx.x] = pooled[row * HD + lane];
    __syncthreads();
    const float* spw = sp + (threadIdx.x & 192);
    float acc = 0.f;
    #pragma unroll
    for (int k4 = 0; k4 < 16; ++k4) {
        float4 xv = reinterpret_cast<const float4*>(spw)[k4];
        int kb = k4 * 4;
        acc = fmaf(xv.x, lin_w[(kb + 0) * HD + lane], acc);
        acc = fmaf(xv.y, lin_w[(kb + 1) * HD + lane], acc);
        acc = fmaf(xv.z, lin_w[(kb + 2) * HD + lane], acc);
        acc = fmaf(xv.w, lin_w[(kb + 3) * HD + lane], acc);
    }
    out[row * HD + lane] = acc + lin_b[lane];
}

extern "C" void kernel_launch(void* const* d_in, const int* in_sizes, int n_in,
                              void* d_out, int out_size, void* d_ws, size_t ws_size,
                              hipStream_t stream)
{
    const float* x     = (const float*)d_in[0];
    const int*  ei     = (const int*)d_in[1];
    const int*  batch  = (const int*)d_in[2];
    const float* W[3]  = {(const float*)d_in[3], (const float*)d_in[7],  (const float*)d_in[11]};
    const float* as[3] = {(const float*)d_in[4], (const float*)d_in[8],  (const float*)d_in[12]};
    const float* ad[3] = {(const float*)d_in[5], (const float*)d_in[9],  (const float*)d_in[13]};
    const float* bb[3] = {(const float*)d_in[6], (const float*)d_in[10], (const float*)d_in[14]};
    const float* gate_w = (const float*)d_in[15];
    const float* gate_b = (const float*)d_in[16];
    const float* lin_w  = (const float*)d_in[17];
    const float* lin_b  = (const float*)d_in[18];
    float* out = (float*)d_out;

    const int* esrc = ei;
    const int* edst = ei + NE;

    float* ws = (float*)d_ws;
    size_t off = 0;
    float* hraw_a = ws + off; off += (size_t)NN * HD;
    float* hraw_b = ws + off; off += (size_t)NN * HD;
    float* denom  = ws + off; off += NN;
    float* gden   = ws + off; off += NG;
    float* pooled = ws + off; off += (size_t)NG * HD;
    size_t zero_floats = off;               // everything above needs zero-init
    float* hfeat   = ws + off; off += (size_t)NN * HD;
    float* alpha_s = ws + off; off += NN;
    float* alpha_d = ws + off; off += NN;
    float* gvals   = ws + off; off += NN;

    hipMemsetAsync(ws, 0, zero_floats * sizeof(float), stream);

    dim3 blk(256);
    const int nodeBlocks = NN / 4;                    // 25000, exact
    const int edgeThreadBlocks = (NETOT + 255) / 256; // 4297
    const int edgeWaveBlocks = NETOT / 4;             // 275000, exact

    // layer l: in = (l==0 ? x : prev raw out), out = routs[l]
    float* rins[3]  = {nullptr, hraw_a, hraw_b};
    float* routs[3] = {hraw_a, hraw_b, hraw_a};

    for (int l = 0; l < 3; ++l) {
        const float* inp = (l == 0) ? x : rins[l];
        const float* bp  = (l == 0) ? bb[0] /*unused*/ : bb[l - 1];
        k_transform<<<nodeBlocks, blk, 0, stream>>>(inp, bp, W[l], as[l], ad[l],
                                                    hfeat, alpha_s, alpha_d, l > 0);
        if (l > 0) hipMemsetAsync(denom, 0, NN * sizeof(float), stream);
        if (l == 2) hipMemsetAsync(hraw_a, 0, (size_t)NN * HD * sizeof(float), stream);
        k_edge_denom<<<edgeThreadBlocks, blk, 0, stream>>>(esrc, edst, alpha_s, alpha_d, denom);
        k_edge_aggr<<<edgeWaveBlocks, blk, 0, stream>>>(esrc, edst, alpha_s, alpha_d,
                                                        denom, hfeat, routs[l]);
    }

    k_gate<<<nodeBlocks, blk, 0, stream>>>(hraw_a, bb[2], gate_w, gate_b, batch, gvals, gden);
    k_pool<<<nodeBlocks, blk, 0, stream>>>(hraw_a, bb[2], gvals, gden, batch, pooled);
    k_final<<<32, blk, 0, stream>>>(pooled, lin_w, lin_b, out);
}

// Round 2
// 1123.312 us; speedup vs baseline: 1.5476x; 1.5476x over previous
//
#include <hip/hip_runtime.h>
#include <math.h>

#define NN 100000      // nodes
#define NE 1000000     // edges (without self loops)
#define NETOT 1100000  // edges + self loops
#define HD 64          // hidden / feature dim
#define NG 128         // graphs
#define NEG_SLOPE 0.2f

// xe = layer0 ? inp[node] : relu(inp[node]/denom_prev[node] + bias_prev)
// h = xe @ W ; alpha_s = h . a_src ; alpha_d = h . a_dst
// Also zero-inits next accumulators: hagg_out[node,:] = 0, denom_out[node] = 0.
__global__ __launch_bounds__(256) void k_transform(
    const float* __restrict__ inp, const float* __restrict__ denom_prev,
    const float* __restrict__ bias_prev,
    const float* __restrict__ W, const float* __restrict__ a_src,
    const float* __restrict__ a_dst, float* __restrict__ h,
    float* __restrict__ alpha_s, float* __restrict__ alpha_d,
    float* __restrict__ hagg_out, float* __restrict__ denom_out, int layer0)
{
    __shared__ float sx[256];
    int node = (blockIdx.x * 256 + threadIdx.x) >> 6;
    int lane = threadIdx.x & 63;
    float xe = inp[(size_t)node * HD + lane];
    if (!layer0) {
        xe = xe / denom_prev[node] + bias_prev[lane];
        xe = xe > 0.f ? xe : 0.f;
    }
    sx[threadIdx.x] = xe;
    hagg_out[(size_t)node * HD + lane] = 0.f;
    if (lane == 0) denom_out[node] = 0.f;
    __syncthreads();
    const float* sxw = sx + (threadIdx.x & 192);   // this wave's row of 64
    float hj = 0.f;
    #pragma unroll
    for (int k4 = 0; k4 < 16; ++k4) {
        float4 xv = reinterpret_cast<const float4*>(sxw)[k4];
        int kb = k4 * 4;
        hj = fmaf(xv.x, W[(kb + 0) * HD + lane], hj);
        hj = fmaf(xv.y, W[(kb + 1) * HD + lane], hj);
        hj = fmaf(xv.z, W[(kb + 2) * HD + lane], hj);
        hj = fmaf(xv.w, W[(kb + 3) * HD + lane], hj);
    }
    h[(size_t)node * HD + lane] = hj;
    float s = hj * a_src[lane];
    float d = hj * a_dst[lane];
    #pragma unroll
    for (int off = 32; off > 0; off >>= 1) {
        s += __shfl_xor(s, off, 64);
        d += __shfl_xor(d, off, 64);
    }
    if (lane == 0) { alpha_s[node] = s; alpha_d[node] = d; }
}

// One wave per edge: w = exp(leaky_relu(as[s]+ad[d]));
// hout[d,:] += w*h[s,:]; denom[d] += w.  (unnormalized accumulation)
__global__ __launch_bounds__(256) void k_edge_aggr(
    const int* __restrict__ esrc, const int* __restrict__ edst,
    const float* __restrict__ alpha_s, const float* __restrict__ alpha_d,
    const float* __restrict__ h, float* __restrict__ hout,
    float* __restrict__ denom)
{
    int wid = (blockIdx.x * 256 + threadIdx.x) >> 6;
    int lane = threadIdx.x & 63;
    int s, d;
    if (wid < NE) { s = esrc[wid]; d = edst[wid]; } else { s = wid - NE; d = s; }
    float ev = alpha_s[s] + alpha_d[d];
    ev = ev > 0.f ? ev : NEG_SLOPE * ev;
    float w = __expf(ev);
    atomicAdd(&hout[(size_t)d * HD + lane], w * h[(size_t)s * HD + lane]);
    if (lane == 0) atomicAdd(&denom[d], w);
}

// h3 = hagg/denom + b2 (final layer output, no relu); store h3; gate score per node.
__global__ __launch_bounds__(256) void k_gate(
    const float* __restrict__ hagg, const float* __restrict__ denom,
    const float* __restrict__ b2, const float* __restrict__ gate_w,
    const float* __restrict__ gate_b, float* __restrict__ h3out,
    float* __restrict__ gvals)
{
    int node = (blockIdx.x * 256 + threadIdx.x) >> 6;
    int lane = threadIdx.x & 63;
    float h3 = hagg[(size_t)node * HD + lane] / denom[node] + b2[lane];
    h3out[(size_t)node * HD + lane] = h3;
    float s = h3 * gate_w[lane];
    #pragma unroll
    for (int off = 32; off > 0; off >>= 1) s += __shfl_xor(s, off, 64);
    if (lane == 0) gvals[node] = s + gate_b[0];
}

__device__ __forceinline__ int lower_bound_batch(const int* __restrict__ batch, int val) {
    int lo = 0, hi = NN;
    while (lo < hi) { int mid = (lo + hi) >> 1; if (batch[mid] < val) lo = mid + 1; else hi = mid; }
    return lo;
}

// One block per graph: softmax-pool over its contiguous node range, then
// fused out[g,:] = pooled @ lin_w + lin_b.
__global__ __launch_bounds__(256) void k_pool(
    const float* __restrict__ h3, const float* __restrict__ gvals,
    const int* __restrict__ batch, const float* __restrict__ lin_w,
    const float* __restrict__ lin_b, float* __restrict__ out)
{
    __shared__ float red[256];
    __shared__ float pooled[HD];
    __shared__ float s_sumexp;
    int g = blockIdx.x;
    int tid = threadIdx.x;
    int start = lower_bound_batch(batch, g);
    int end   = lower_bound_batch(batch, g + 1);

    // phase 1: sum of exp(gate) over the graph's nodes
    float local = 0.f;
    for (int n = start + tid; n < end; n += 256) local += __expf(gvals[n]);
    red[tid] = local;
    __syncthreads();
    #pragma unroll
    for (int s = 128; s > 0; s >>= 1) {
        if (tid < s) red[tid] += red[tid + s];
        __syncthreads();
    }
    if (tid == 0) s_sumexp = red[0];
    __syncthreads();
    float inv = 1.f / s_sumexp;

    // phase 2: weighted feature sum, wave per node, lane = channel
    int wid = tid >> 6, lane = tid & 63;
    float acc = 0.f;
    for (int n = start + wid; n < end; n += 4) {
        float c = __expf(gvals[n]) * inv;
        acc = fmaf(c, h3[(size_t)n * HD + lane], acc);
    }
    __syncthreads();   // red[] reuse
    red[tid] = acc;
    __syncthreads();
    if (tid < 64) pooled[tid] = red[tid] + red[tid + 64] + red[tid + 128] + red[tid + 192];
    __syncthreads();

    // phase 3: out[g,:] = pooled @ lin_w + lin_b (threads 0..63, one output col each)
    if (tid < 64) {
        float o = lin_b[tid];
        #pragma unroll 8
        for (int c = 0; c < HD; ++c) o = fmaf(pooled[c], lin_w[c * HD + tid], o);
        out[g * HD + tid] = o;
    }
}

extern "C" void kernel_launch(void* const* d_in, const int* in_sizes, int n_in,
                              void* d_out, int out_size, void* d_ws, size_t ws_size,
                              hipStream_t stream)
{
    const float* x     = (const float*)d_in[0];
    const int*  ei     = (const int*)d_in[1];
    const int*  batch  = (const int*)d_in[2];
    const float* W[3]  = {(const float*)d_in[3], (const float*)d_in[7],  (const float*)d_in[11]};
    const float* as[3] = {(const float*)d_in[4], (const float*)d_in[8],  (const float*)d_in[12]};
    const float* ad[3] = {(const float*)d_in[5], (const float*)d_in[9],  (const float*)d_in[13]};
    const float* bb[3] = {(const float*)d_in[6], (const float*)d_in[10], (const float*)d_in[14]};
    const float* gate_w = (const float*)d_in[15];
    const float* gate_b = (const float*)d_in[16];
    const float* lin_w  = (const float*)d_in[17];
    const float* lin_b  = (const float*)d_in[18];
    float* out = (float*)d_out;

    const int* esrc = ei;
    const int* edst = ei + NE;

    float* ws = (float*)d_ws;
    size_t off = 0;
    float* hagg_a  = ws + off; off += (size_t)NN * HD;
    float* hagg_b  = ws + off; off += (size_t)NN * HD;
    float* hfeat   = ws + off; off += (size_t)NN * HD;   // h (per layer), then h3
    float* denom_a = ws + off; off += NN;
    float* denom_b = ws + off; off += NN;
    float* alpha_s = ws + off; off += NN;
    float* alpha_d = ws + off; off += NN;
    float* gvals   = ws + off; off += NN;

    dim3 blk(256);
    const int nodeBlocks = NN / 4;        // 25000, exact
    const int edgeWaveBlocks = NETOT / 4; // 275000, exact

    // layer l reads rins[l] (+denom of l-1), writes routs[l] (+denom of l)
    const float* rins[3]  = {x, hagg_a, hagg_b};
    float* routs[3]       = {hagg_a, hagg_b, hagg_a};
    float* dens[3]        = {denom_a, denom_b, denom_a};

    for (int l = 0; l < 3; ++l) {
        const float* dprev = (l == 0) ? denom_a /*unused*/ : dens[l - 1];
        const float* bprev = (l == 0) ? bb[0]   /*unused*/ : bb[l - 1];
        k_transform<<<nodeBlocks, blk, 0, stream>>>(rins[l], dprev, bprev,
                                                    W[l], as[l], ad[l],
                                                    hfeat, alpha_s, alpha_d,
                                                    routs[l], dens[l], l == 0);
        k_edge_aggr<<<edgeWaveBlocks, blk, 0, stream>>>(esrc, edst, alpha_s, alpha_d,
                                                        hfeat, routs[l], dens[l]);
    }

    // hagg_a + denom_a hold layer-2 unnormalized output
    k_gate<<<nodeBlocks, blk, 0, stream>>>(hagg_a, denom_a, bb[2], gate_w, gate_b,
                                           hfeat /*h3*/, gvals);
    k_pool<<<NG, blk, 0, stream>>>(hfeat, gvals, batch, lin_w, lin_b, out);
}

// Round 3
// 596.453 us; speedup vs baseline: 2.9146x; 1.8833x over previous
//
#include <hip/hip_runtime.h>
#include <math.h>

#define NN 100000      // nodes
#define NE 1000000     // edges (without self loops)
#define NETOT 1100000  // edges + self loops
#define HD 64          // hidden / feature dim
#define NG 128         // graphs
#define NEG_SLOPE 0.2f
#define NBLK 391       // ceil(NN/256)

// ---------------- CSR build ----------------

__global__ __launch_bounds__(256) void k_deg_init(int* __restrict__ deg) {
    int n = blockIdx.x * 256 + threadIdx.x;
    if (n < NN) deg[n] = 1;   // self-loop
}

__global__ __launch_bounds__(256) void k_hist(const int* __restrict__ edst,
                                              int* __restrict__ deg) {
    int e = blockIdx.x * 256 + threadIdx.x;
    if (e < NE) atomicAdd(&deg[edst[e]], 1);
}

__global__ __launch_bounds__(256) void k_bsum(const int* __restrict__ deg,
                                              int* __restrict__ bsum) {
    __shared__ int sm[256];
    int i = blockIdx.x * 256 + threadIdx.x;
    sm[threadIdx.x] = (i < NN) ? deg[i] : 0;
    __syncthreads();
    #pragma unroll
    for (int s = 128; s > 0; s >>= 1) {
        if (threadIdx.x < s) sm[threadIdx.x] += sm[threadIdx.x + s];
        __syncthreads();
    }
    if (threadIdx.x == 0) bsum[blockIdx.x] = sm[0];
}

// single block, 512 threads: exclusive scan of NBLK block sums
__global__ __launch_bounds__(512) void k_scanb(const int* __restrict__ bsum,
                                               int* __restrict__ boff) {
    __shared__ int sm[512];
    int t = threadIdx.x;
    int v = (t < NBLK) ? bsum[t] : 0;
    sm[t] = v;
    __syncthreads();
    #pragma unroll
    for (int s = 1; s < 512; s <<= 1) {
        int add = (t >= s) ? sm[t - s] : 0;
        __syncthreads();
        sm[t] += add;
        __syncthreads();
    }
    if (t < NBLK) boff[t] = sm[t] - v;   // exclusive
}

__global__ __launch_bounds__(256) void k_scan2(const int* __restrict__ deg,
                                               const int* __restrict__ boff,
                                               int* __restrict__ row,
                                               int* __restrict__ cursor) {
    __shared__ int sm[256];
    int t = threadIdx.x, i = blockIdx.x * 256 + t;
    int v = (i < NN) ? deg[i] : 0;
    sm[t] = v;
    __syncthreads();
    #pragma unroll
    for (int s = 1; s < 256; s <<= 1) {
        int add = (t >= s) ? sm[t - s] : 0;
        __syncthreads();
        sm[t] += add;
        __syncthreads();
    }
    int excl = boff[blockIdx.x] + sm[t] - v;
    if (i < NN) { row[i] = excl; cursor[i] = excl; }
    if (i == NN - 1) row[NN] = excl + v;
}

__global__ __launch_bounds__(256) void k_scatter(const int* __restrict__ esrc,
                                                 const int* __restrict__ edst,
                                                 int* __restrict__ cursor,
                                                 int* __restrict__ ssrc) {
    int e = blockIdx.x * 256 + threadIdx.x;
    if (e >= NETOT) return;
    int s, d;
    if (e < NE) { s = esrc[e]; d = edst[e]; } else { s = e - NE; d = s; }
    int pos = atomicAdd(&cursor[d], 1);
    ssrc[pos] = s;
}

// ---------------- per-layer kernels ----------------

// xe = layer0 ? inp : relu(inp + bias_prev)    (inp is already normalized agg)
// h = xe @ W ; alpha_s = h . a_src ; alpha_d = h . a_dst
__global__ __launch_bounds__(256) void k_transform(
    const float* __restrict__ inp, const float* __restrict__ bias_prev,
    const float* __restrict__ W, const float* __restrict__ a_src,
    const float* __restrict__ a_dst, float* __restrict__ h,
    float* __restrict__ alpha_s, float* __restrict__ alpha_d, int layer0)
{
    __shared__ float sx[256];
    int node = (blockIdx.x * 256 + threadIdx.x) >> 6;
    int lane = threadIdx.x & 63;
    float xe = inp[(size_t)node * HD + lane];
    if (!layer0) {
        xe += bias_prev[lane];
        xe = xe > 0.f ? xe : 0.f;
    }
    sx[threadIdx.x] = xe;
    __syncthreads();
    const float* sxw = sx + (threadIdx.x & 192);   // this wave's row of 64
    float hj = 0.f;
    #pragma unroll
    for (int k4 = 0; k4 < 16; ++k4) {
        float4 xv = reinterpret_cast<const float4*>(sxw)[k4];
        int kb = k4 * 4;
        hj = fmaf(xv.x, W[(kb + 0) * HD + lane], hj);
        hj = fmaf(xv.y, W[(kb + 1) * HD + lane], hj);
        hj = fmaf(xv.z, W[(kb + 2) * HD + lane], hj);
        hj = fmaf(xv.w, W[(kb + 3) * HD + lane], hj);
    }
    h[(size_t)node * HD + lane] = hj;
    float s = hj * a_src[lane];
    float d = hj * a_dst[lane];
    #pragma unroll
    for (int off = 32; off > 0; off >>= 1) {
        s += __shfl_xor(s, off, 64);
        d += __shfl_xor(d, off, 64);
    }
    if (lane == 0) { alpha_s[node] = s; alpha_d[node] = d; }
}

// One wave per dst node: walk CSR edge list, accumulate in registers,
// write NORMALIZED aggregation once. No atomics.
__global__ __launch_bounds__(256) void k_aggr(
    const int* __restrict__ row, const int* __restrict__ ssrc,
    const float* __restrict__ alpha_s, const float* __restrict__ alpha_d,
    const float* __restrict__ h, float* __restrict__ hout)
{
    int node = (blockIdx.x * 256 + threadIdx.x) >> 6;
    int lane = threadIdx.x & 63;
    int beg = row[node], end = row[node + 1];
    float ad = alpha_d[node];
    float acc = 0.f, den = 0.f;
    int s_next = ssrc[beg];
    for (int i = beg; i < end; ++i) {
        int s = s_next;
        if (i + 1 < end) s_next = ssrc[i + 1];
        float ev = alpha_s[s] + ad;
        ev = ev > 0.f ? ev : NEG_SLOPE * ev;
        float w = __expf(ev);
        acc = fmaf(w, h[(size_t)s * HD + lane], acc);
        den += w;
    }
    hout[(size_t)node * HD + lane] = acc / den;   // den>0: self-loop
}

// h3 = hagg + b2 (final layer, already normalized); gate score per node
__global__ __launch_bounds__(256) void k_gate(
    const float* __restrict__ hagg, const float* __restrict__ b2,
    const float* __restrict__ gate_w, const float* __restrict__ gate_b,
    float* __restrict__ h3out, float* __restrict__ gvals)
{
    int node = (blockIdx.x * 256 + threadIdx.x) >> 6;
    int lane = threadIdx.x & 63;
    float h3 = hagg[(size_t)node * HD + lane] + b2[lane];
    h3out[(size_t)node * HD + lane] = h3;
    float s = h3 * gate_w[lane];
    #pragma unroll
    for (int off = 32; off > 0; off >>= 1) s += __shfl_xor(s, off, 64);
    if (lane == 0) gvals[node] = s + gate_b[0];
}

__device__ __forceinline__ int lower_bound_batch(const int* __restrict__ batch, int val) {
    int lo = 0, hi = NN;
    while (lo < hi) { int mid = (lo + hi) >> 1; if (batch[mid] < val) lo = mid + 1; else hi = mid; }
    return lo;
}

// One block per graph: softmax-pool + fused final linear
__global__ __launch_bounds__(256) void k_pool(
    const float* __restrict__ h3, const float* __restrict__ gvals,
    const int* __restrict__ batch, const float* __restrict__ lin_w,
    const float* __restrict__ lin_b, float* __restrict__ out)
{
    __shared__ float red[256];
    __shared__ float pooled[HD];
    __shared__ float s_sumexp;
    int g = blockIdx.x;
    int tid = threadIdx.x;
    int start = lower_bound_batch(batch, g);
    int end   = lower_bound_batch(batch, g + 1);

    float local = 0.f;
    for (int n = start + tid; n < end; n += 256) local += __expf(gvals[n]);
    red[tid] = local;
    __syncthreads();
    #pragma unroll
    for (int s = 128; s > 0; s >>= 1) {
        if (tid < s) red[tid] += red[tid + s];
        __syncthreads();
    }
    if (tid == 0) s_sumexp = red[0];
    __syncthreads();
    float inv = 1.f / s_sumexp;

    int wid = tid >> 6, lane = tid & 63;
    float acc = 0.f;
    for (int n = start + wid; n < end; n += 4) {
        float c = __expf(gvals[n]) * inv;
        acc = fmaf(c, h3[(size_t)n * HD + lane], acc);
    }
    __syncthreads();
    red[tid] = acc;
    __syncthreads();
    if (tid < 64) pooled[tid] = red[tid] + red[tid + 64] + red[tid + 128] + red[tid + 192];
    __syncthreads();

    if (tid < 64) {
        float o = lin_b[tid];
        #pragma unroll 8
        for (int c = 0; c < HD; ++c) o = fmaf(pooled[c], lin_w[c * HD + tid], o);
        out[g * HD + tid] = o;
    }
}

extern "C" void kernel_launch(void* const* d_in, const int* in_sizes, int n_in,
                              void* d_out, int out_size, void* d_ws, size_t ws_size,
                              hipStream_t stream)
{
    const float* x     = (const float*)d_in[0];
    const int*  ei     = (const int*)d_in[1];
    const int*  batch  = (const int*)d_in[2];
    const float* W[3]  = {(const float*)d_in[3], (const float*)d_in[7],  (const float*)d_in[11]};
    const float* as[3] = {(const float*)d_in[4], (const float*)d_in[8],  (const float*)d_in[12]};
    const float* ad[3] = {(const float*)d_in[5], (const float*)d_in[9],  (const float*)d_in[13]};
    const float* bb[3] = {(const float*)d_in[6], (const float*)d_in[10], (const float*)d_in[14]};
    const float* gate_w = (const float*)d_in[15];
    const float* gate_b = (const float*)d_in[16];
    const float* lin_w  = (const float*)d_in[17];
    const float* lin_b  = (const float*)d_in[18];
    float* out = (float*)d_out;

    const int* esrc = ei;
    const int* edst = ei + NE;

    float* wsf = (float*)d_ws;
    size_t off = 0;
    float* buf0    = wsf + off; off += (size_t)NN * HD;   // agg output / layer input
    float* buf1    = wsf + off; off += (size_t)NN * HD;   // h, then h3
    float* alpha_s = wsf + off; off += NN;
    float* alpha_d = wsf + off; off += NN;
    float* gvals   = wsf + off; off += NN;
    int* wsi = (int*)(wsf + off);
    size_t ioff = 0;
    int* deg    = wsi + ioff; ioff += NN;      // also reused as nothing else
    int* row    = wsi + ioff; ioff += NN + 1;
    int* cursor = wsi + ioff; ioff += NN;
    int* bsum   = wsi + ioff; ioff += NBLK;
    int* boff   = wsi + ioff; ioff += NBLK;
    int* ssrc   = wsi + ioff; ioff += NETOT;

    dim3 blk(256);
    const int nodeBlocks  = NN / 4;              // 25000 (wave per node)
    const int nodeBlocks1 = (NN + 255) / 256;    // 391 (thread per node)
    const int edgeBlocks  = (NE + 255) / 256;
    const int edgeBlocksT = (NETOT + 255) / 256;

    // ---- CSR build (once per call) ----
    k_deg_init<<<nodeBlocks1, blk, 0, stream>>>(deg);
    k_hist<<<edgeBlocks, blk, 0, stream>>>(edst, deg);
    k_bsum<<<NBLK, blk, 0, stream>>>(deg, bsum);
    k_scanb<<<1, 512, 0, stream>>>(bsum, boff);
    k_scan2<<<NBLK, blk, 0, stream>>>(deg, boff, row, cursor);
    k_scatter<<<edgeBlocksT, blk, 0, stream>>>(esrc, edst, cursor, ssrc);

    // ---- 3 GAT layers ----
    for (int l = 0; l < 3; ++l) {
        const float* inp  = (l == 0) ? x : buf0;
        const float* bprev = (l == 0) ? bb[0] /*unused*/ : bb[l - 1];
        k_transform<<<nodeBlocks, blk, 0, stream>>>(inp, bprev, W[l], as[l], ad[l],
                                                    buf1, alpha_s, alpha_d, l == 0);
        k_aggr<<<nodeBlocks, blk, 0, stream>>>(row, ssrc, alpha_s, alpha_d, buf1, buf0);
    }

    // ---- pooling + final linear ----
    k_gate<<<nodeBlocks, blk, 0, stream>>>(buf0, bb[2], gate_w, gate_b, buf1, gvals);
    k_pool<<<NG, blk, 0, stream>>>(buf1, gvals, batch, lin_w, lin_b, out);
}

// Round 4
// 563.803 us; speedup vs baseline: 3.0834x; 1.0579x over previous
//
#include <hip/hip_runtime.h>
#include <hip/hip_bf16.h>
#include <math.h>

#define NN 100000      // nodes
#define NE 1000000     // edges (without self loops)
#define NETOT 1100000  // edges + self loops
#define HD 64          // hidden / feature dim
#define NG 128         // graphs
#define NEG_SLOPE 0.2f
#define NBLK 391       // ceil(NN/256)

// ---------------- CSR build ----------------

__global__ __launch_bounds__(256) void k_deg_init(int* __restrict__ deg) {
    int n = blockIdx.x * 256 + threadIdx.x;
    if (n < NN) deg[n] = 1;   // self-loop
}

__global__ __launch_bounds__(256) void k_hist(const int* __restrict__ edst,
                                              int* __restrict__ deg) {
    int e = blockIdx.x * 256 + threadIdx.x;
    if (e < NE) atomicAdd(&deg[edst[e]], 1);
}

__global__ __launch_bounds__(256) void k_bsum(const int* __restrict__ deg,
                                              int* __restrict__ bsum) {
    __shared__ int sm[256];
    int i = blockIdx.x * 256 + threadIdx.x;
    sm[threadIdx.x] = (i < NN) ? deg[i] : 0;
    __syncthreads();
    #pragma unroll
    for (int s = 128; s > 0; s >>= 1) {
        if (threadIdx.x < s) sm[threadIdx.x] += sm[threadIdx.x + s];
        __syncthreads();
    }
    if (threadIdx.x == 0) bsum[blockIdx.x] = sm[0];
}

// single block, 512 threads: exclusive scan of NBLK block sums
__global__ __launch_bounds__(512) void k_scanb(const int* __restrict__ bsum,
                                               int* __restrict__ boff) {
    __shared__ int sm[512];
    int t = threadIdx.x;
    int v = (t < NBLK) ? bsum[t] : 0;
    sm[t] = v;
    __syncthreads();
    #pragma unroll
    for (int s = 1; s < 512; s <<= 1) {
        int add = (t >= s) ? sm[t - s] : 0;
        __syncthreads();
        sm[t] += add;
        __syncthreads();
    }
    if (t < NBLK) boff[t] = sm[t] - v;   // exclusive
}

__global__ __launch_bounds__(256) void k_scan2(const int* __restrict__ deg,
                                               const int* __restrict__ boff,
                                               int* __restrict__ row,
                                               int* __restrict__ cursor) {
    __shared__ int sm[256];
    int t = threadIdx.x, i = blockIdx.x * 256 + t;
    int v = (i < NN) ? deg[i] : 0;
    sm[t] = v;
    __syncthreads();
    #pragma unroll
    for (int s = 1; s < 256; s <<= 1) {
        int add = (t >= s) ? sm[t - s] : 0;
        __syncthreads();
        sm[t] += add;
        __syncthreads();
    }
    int excl = boff[blockIdx.x] + sm[t] - v;
    if (i < NN) { row[i] = excl; cursor[i] = excl; }
    if (i == NN - 1) row[NN] = excl + v;
}

__global__ __launch_bounds__(256) void k_scatter(const int* __restrict__ esrc,
                                                 const int* __restrict__ edst,
                                                 int* __restrict__ cursor,
                                                 int* __restrict__ ssrc) {
    int e = blockIdx.x * 256 + threadIdx.x;
    if (e >= NETOT) return;
    int s, d;
    if (e < NE) { s = esrc[e]; d = edst[e]; } else { s = e - NE; d = s; }
    int pos = atomicAdd(&cursor[d], 1);
    ssrc[pos] = s;
}

// ---------------- per-layer kernels ----------------

// xe = layer0 ? inp : relu(inp + bias_prev)    (inp is already normalized agg)
// h(bf16) = xe @ W ; alpha_s = h . a_src ; alpha_d = h . a_dst (fp32, pre-round)
__global__ __launch_bounds__(256) void k_transform(
    const float* __restrict__ inp, const float* __restrict__ bias_prev,
    const float* __restrict__ W, const float* __restrict__ a_src,
    const float* __restrict__ a_dst, __hip_bfloat16* __restrict__ hb,
    float* __restrict__ alpha_s, float* __restrict__ alpha_d, int layer0)
{
    __shared__ float sx[256];
    int node = (blockIdx.x * 256 + threadIdx.x) >> 6;
    int lane = threadIdx.x & 63;
    float xe = inp[(size_t)node * HD + lane];
    if (!layer0) {
        xe += bias_prev[lane];
        xe = xe > 0.f ? xe : 0.f;
    }
    sx[threadIdx.x] = xe;
    __syncthreads();
    const float* sxw = sx + (threadIdx.x & 192);   // this wave's row of 64
    float hj = 0.f;
    #pragma unroll
    for (int k4 = 0; k4 < 16; ++k4) {
        float4 xv = reinterpret_cast<const float4*>(sxw)[k4];
        int kb = k4 * 4;
        hj = fmaf(xv.x, W[(kb + 0) * HD + lane], hj);
        hj = fmaf(xv.y, W[(kb + 1) * HD + lane], hj);
        hj = fmaf(xv.z, W[(kb + 2) * HD + lane], hj);
        hj = fmaf(xv.w, W[(kb + 3) * HD + lane], hj);
    }
    hb[(size_t)node * HD + lane] = __float2bfloat16(hj);
    float s = hj * a_src[lane];
    float d = hj * a_dst[lane];
    #pragma unroll
    for (int off = 32; off > 0; off >>= 1) {
        s += __shfl_xor(s, off, 64);
        d += __shfl_xor(d, off, 64);
    }
    if (lane == 0) { alpha_s[node] = s; alpha_d[node] = d; }
}

// One wave per dst node: walk CSR edge list, accumulate fp32 in registers from
// bf16 h, write NORMALIZED aggregation once. No atomics.
// last!=0: fuse gate: h3 = agg + b2 -> h3out, gvals = h3.gate_w + gate_b.
__global__ __launch_bounds__(256) void k_aggr(
    const int* __restrict__ row, const int* __restrict__ ssrc,
    const float* __restrict__ alpha_s, const float* __restrict__ alpha_d,
    const __hip_bfloat16* __restrict__ hb, float* __restrict__ hout,
    const float* __restrict__ b2, const float* __restrict__ gate_w,
    const float* __restrict__ gate_b, float* __restrict__ h3out,
    float* __restrict__ gvals, int last)
{
    int node = (blockIdx.x * 256 + threadIdx.x) >> 6;
    int lane = threadIdx.x & 63;
    int beg = row[node], end = row[node + 1];
    float ad = alpha_d[node];
    float acc = 0.f, den = 0.f;
    int i = beg;
    for (; i + 2 <= end; i += 2) {
        int s0 = ssrc[i], s1 = ssrc[i + 1];
        float e0 = alpha_s[s0] + ad, e1 = alpha_s[s1] + ad;
        e0 = e0 > 0.f ? e0 : NEG_SLOPE * e0;
        e1 = e1 > 0.f ? e1 : NEG_SLOPE * e1;
        float w0 = __expf(e0), w1 = __expf(e1);
        float h0 = __bfloat162float(hb[(size_t)s0 * HD + lane]);
        float h1 = __bfloat162float(hb[(size_t)s1 * HD + lane]);
        acc = fmaf(w0, h0, acc);
        acc = fmaf(w1, h1, acc);
        den += w0 + w1;
    }
    if (i < end) {
        int s0 = ssrc[i];
        float e0 = alpha_s[s0] + ad;
        e0 = e0 > 0.f ? e0 : NEG_SLOPE * e0;
        float w0 = __expf(e0);
        acc = fmaf(w0, __bfloat162float(hb[(size_t)s0 * HD + lane]), acc);
        den += w0;
    }
    float hn = acc / den;   // den>0: self-loop guarantees >=1 edge
    if (!last) {
        hout[(size_t)node * HD + lane] = hn;
    } else {
        float h3 = hn + b2[lane];
        h3out[(size_t)node * HD + lane] = h3;
        float s = h3 * gate_w[lane];
        #pragma unroll
        for (int off = 32; off > 0; off >>= 1) s += __shfl_xor(s, off, 64);
        if (lane == 0) gvals[node] = s + gate_b[0];
    }
}

__device__ __forceinline__ int lower_bound_batch(const int* __restrict__ batch, int val) {
    int lo = 0, hi = NN;
    while (lo < hi) { int mid = (lo + hi) >> 1; if (batch[mid] < val) lo = mid + 1; else hi = mid; }
    return lo;
}

// One block per graph: softmax-pool + fused final linear
__global__ __launch_bounds__(256) void k_pool(
    const float* __restrict__ h3, const float* __restrict__ gvals,
    const int* __restrict__ batch, const float* __restrict__ lin_w,
    const float* __restrict__ lin_b, float* __restrict__ out)
{
    __shared__ float red[256];
    __shared__ float pooled[HD];
    __shared__ float s_sumexp;
    int g = blockIdx.x;
    int tid = threadIdx.x;
    int start = lower_bound_batch(batch, g);
    int end   = lower_bound_batch(batch, g + 1);

    float local = 0.f;
    for (int n = start + tid; n < end; n += 256) local += __expf(gvals[n]);
    red[tid] = local;
    __syncthreads();
    #pragma unroll
    for (int s = 128; s > 0; s >>= 1) {
        if (tid < s) red[tid] += red[tid + s];
        __syncthreads();
    }
    if (tid == 0) s_sumexp = red[0];
    __syncthreads();
    float inv = 1.f / s_sumexp;

    int wid = tid >> 6, lane = tid & 63;
    float acc = 0.f;
    for (int n = start + wid; n < end; n += 4) {
        float c = __expf(gvals[n]) * inv;
        acc = fmaf(c, h3[(size_t)n * HD + lane], acc);
    }
    __syncthreads();
    red[tid] = acc;
    __syncthreads();
    if (tid < 64) pooled[tid] = red[tid] + red[tid + 64] + red[tid + 128] + red[tid + 192];
    __syncthreads();

    if (tid < 64) {
        float o = lin_b[tid];
        #pragma unroll 8
        for (int c = 0; c < HD; ++c) o = fmaf(pooled[c], lin_w[c * HD + tid], o);
        out[g * HD + tid] = o;
    }
}

extern "C" void kernel_launch(void* const* d_in, const int* in_sizes, int n_in,
                              void* d_out, int out_size, void* d_ws, size_t ws_size,
                              hipStream_t stream)
{
    const float* x     = (const float*)d_in[0];
    const int*  ei     = (const int*)d_in[1];
    const int*  batch  = (const int*)d_in[2];
    const float* W[3]  = {(const float*)d_in[3], (const float*)d_in[7],  (const float*)d_in[11]};
    const float* as[3] = {(const float*)d_in[4], (const float*)d_in[8],  (const float*)d_in[12]};
    const float* ad[3] = {(const float*)d_in[5], (const float*)d_in[9],  (const float*)d_in[13]};
    const float* bb[3] = {(const float*)d_in[6], (const float*)d_in[10], (const float*)d_in[14]};
    const float* gate_w = (const float*)d_in[15];
    const float* gate_b = (const float*)d_in[16];
    const float* lin_w  = (const float*)d_in[17];
    const float* lin_b  = (const float*)d_in[18];
    float* out = (float*)d_out;

    const int* esrc = ei;
    const int* edst = ei + NE;

    float* wsf = (float*)d_ws;
    size_t off = 0;
    float* buf0    = wsf + off; off += (size_t)NN * HD;   // agg output / layer input
    float* buf1    = wsf + off; off += (size_t)NN * HD;   // h3 (final)
    float* alpha_s = wsf + off; off += NN;
    float* alpha_d = wsf + off; off += NN;
    float* gvals   = wsf + off; off += NN;
    __hip_bfloat16* hb = (__hip_bfloat16*)(wsf + off); off += (size_t)NN * HD / 2;
    int* wsi = (int*)(wsf + off);
    size_t ioff = 0;
    int* deg    = wsi + ioff; ioff += NN;
    int* row    = wsi + ioff; ioff += NN + 1;
    int* cursor = wsi + ioff; ioff += NN;
    int* bsum   = wsi + ioff; ioff += NBLK;
    int* boff   = wsi + ioff; ioff += NBLK;
    int* ssrc   = wsi + ioff; ioff += NETOT;

    dim3 blk(256);
    const int nodeBlocks  = NN / 4;              // 25000 (wave per node)
    const int nodeBlocks1 = (NN + 255) / 256;    // 391 (thread per node)
    const int edgeBlocks  = (NE + 255) / 256;
    const int edgeBlocksT = (NETOT + 255) / 256;

    // ---- CSR build (once per call) ----
    k_deg_init<<<nodeBlocks1, blk, 0, stream>>>(deg);
    k_hist<<<edgeBlocks, blk, 0, stream>>>(edst, deg);
    k_bsum<<<NBLK, blk, 0, stream>>>(deg, bsum);
    k_scanb<<<1, 512, 0, stream>>>(bsum, boff);
    k_scan2<<<NBLK, blk, 0, stream>>>(deg, boff, row, cursor);
    k_scatter<<<edgeBlocksT, blk, 0, stream>>>(esrc, edst, cursor, ssrc);

    // ---- 3 GAT layers ----
    for (int l = 0; l < 3; ++l) {
        const float* inp   = (l == 0) ? x : buf0;
        const float* bprev = (l == 0) ? bb[0] /*unused*/ : bb[l - 1];
        k_transform<<<nodeBlocks, blk, 0, stream>>>(inp, bprev, W[l], as[l], ad[l],
                                                    hb, alpha_s, alpha_d, l == 0);
        k_aggr<<<nodeBlocks, blk, 0, stream>>>(row, ssrc, alpha_s, alpha_d, hb, buf0,
                                               bb[2], gate_w, gate_b, buf1, gvals,
                                               l == 2);
    }

    // ---- pooling + final linear ----
    k_pool<<<NG, blk, 0, stream>>>(buf1, gvals, batch, lin_w, lin_b, out);
}

// Round 6
// 546.971 us; speedup vs baseline: 3.1782x; 1.0308x over previous
//
#include <hip/hip_runtime.h>
#include <hip/hip_bf16.h>
#include <math.h>

#define NN 100000      // nodes
#define NE 1000000     // real edges (self-loops handled analytically)
#define HD 64          // hidden / feature dim
#define NG 128         // graphs
#define NEG_SLOPE 0.2f
#define NBLK 391       // ceil(NN/256)

__device__ __forceinline__ float bf2f(unsigned short u) {
    return __uint_as_float(((unsigned)u) << 16);
}
__device__ __forceinline__ unsigned short f2bf(float f) {
    __hip_bfloat16 h = __float2bfloat16(f);
    return *reinterpret_cast<unsigned short*>(&h);
}

// ---------------- CSR build (real edges only; deg memset to 0 outside) ----

__global__ __launch_bounds__(256) void k_hist(const int* __restrict__ edst,
                                              int* __restrict__ deg) {
    int e = blockIdx.x * 256 + threadIdx.x;
    if (e < NE) atomicAdd(&deg[edst[e]], 1);
}

__global__ __launch_bounds__(256) void k_bsum(const int* __restrict__ deg,
                                              int* __restrict__ bsum) {
    __shared__ int sm[256];
    int i = blockIdx.x * 256 + threadIdx.x;
    sm[threadIdx.x] = (i < NN) ? deg[i] : 0;
    __syncthreads();
    #pragma unroll
    for (int s = 128; s > 0; s >>= 1) {
        if (threadIdx.x < s) sm[threadIdx.x] += sm[threadIdx.x + s];
        __syncthreads();
    }
    if (threadIdx.x == 0) bsum[blockIdx.x] = sm[0];
}

__global__ __launch_bounds__(512) void k_scanb(const int* __restrict__ bsum,
                                               int* __restrict__ boff) {
    __shared__ int sm[512];
    int t = threadIdx.x;
    int v = (t < NBLK) ? bsum[t] : 0;
    sm[t] = v;
    __syncthreads();
    #pragma unroll
    for (int s = 1; s < 512; s <<= 1) {
        int add = (t >= s) ? sm[t - s] : 0;
        __syncthreads();
        sm[t] += add;
        __syncthreads();
    }
    if (t < NBLK) boff[t] = sm[t] - v;   // exclusive
}

__global__ __launch_bounds__(256) void k_scan2(const int* __restrict__ deg,
                                               const int* __restrict__ boff,
                                               int* __restrict__ row,
                                               int* __restrict__ cursor) {
    __shared__ int sm[256];
    int t = threadIdx.x, i = blockIdx.x * 256 + t;
    int v = (i < NN) ? deg[i] : 0;
    sm[t] = v;
    __syncthreads();
    #pragma unroll
    for (int s = 1; s < 256; s <<= 1) {
        int add = (t >= s) ? sm[t - s] : 0;
        __syncthreads();
        sm[t] += add;
        __syncthreads();
    }
    int excl = boff[blockIdx.x] + sm[t] - v;
    if (i < NN) { row[i] = excl; cursor[i] = excl; }
    if (i == NN - 1) row[NN] = excl + v;
}

__global__ __launch_bounds__(256) void k_scatter(const int* __restrict__ esrc,
                                                 const int* __restrict__ edst,
                                                 int* __restrict__ cursor,
                                                 int* __restrict__ ssrc) {
    int e = blockIdx.x * 256 + threadIdx.x;
    if (e >= NE) return;
    int s = esrc[e];
    int d = edst[e];
    int pos = atomicAdd(&cursor[d], 1);
    __builtin_nontemporal_store(s, &ssrc[pos]);
}

// ---------------- layer-0 transform (from fp32 x) ----------------
// h(bf16) = x @ W ; alpha_s = h.a_src ; alpha_d = h.a_dst (fp32 pre-round)
__global__ __launch_bounds__(256) void k_transform0(
    const float* __restrict__ inp, const float* __restrict__ W,
    const float* __restrict__ a_src, const float* __restrict__ a_dst,
    unsigned short* __restrict__ hb,
    float* __restrict__ alpha_s, float* __restrict__ alpha_d)
{
    __shared__ float sx[256];
    int node = (blockIdx.x * 256 + threadIdx.x) >> 6;
    int lane = threadIdx.x & 63;
    sx[threadIdx.x] = inp[(size_t)node * HD + lane];
    __syncthreads();
    const float* sxw = sx + (threadIdx.x & 192);
    float hj = 0.f;
    #pragma unroll
    for (int k4 = 0; k4 < 16; ++k4) {
        float4 xv = reinterpret_cast<const float4*>(sxw)[k4];
        int kb = k4 * 4;
        hj = fmaf(xv.x, W[(kb + 0) * HD + lane], hj);
        hj = fmaf(xv.y, W[(kb + 1) * HD + lane], hj);
        hj = fmaf(xv.z, W[(kb + 2) * HD + lane], hj);
        hj = fmaf(xv.w, W[(kb + 3) * HD + lane], hj);
    }
    hb[(size_t)node * HD + lane] = f2bf(hj);
    float s = hj * a_src[lane];
    float d = hj * a_dst[lane];
    #pragma unroll
    for (int off = 32; off > 0; off >>= 1) {
        s += __shfl_xor(s, off, 64);
        d += __shfl_xor(d, off, 64);
    }
    if (lane == 0) { alpha_s[node] = s; alpha_d[node] = d; }
}

// ---------------- fused aggregate (+ next transform / + gate) ----------------
// 2 nodes per wave: half = lane>>5 picks node, hl = lane&31 holds channels
// (2*hl, 2*hl+1) as bf16x2. Gather loop accumulates softmax-weighted sum.

__device__ __forceinline__ void edge_acc(int s, float ad, int hl,
    const float* __restrict__ as_in, const unsigned short* __restrict__ hb_in,
    float& acc0, float& acc1, float& den)
{
    float e = as_in[s] + ad;
    e = e > 0.f ? e : NEG_SLOPE * e;
    float w = __expf(e);
    ushort2 p = reinterpret_cast<const ushort2*>(hb_in)[(size_t)s * 32 + hl];
    acc0 = fmaf(w, bf2f(p.x), acc0);
    acc1 = fmaf(w, bf2f(p.y), acc1);
    den += w;
}

// aggregate layer l, then fused transform of layer l+1:
// xe = relu(agg + bprev); h_next = xe @ Wn (bf16 out); next alphas.
__global__ __launch_bounds__(256) void k_aggr_ft(
    const int* __restrict__ row, const int* __restrict__ ssrc,
    const float* __restrict__ as_in, const float* __restrict__ ad_in,
    const unsigned short* __restrict__ hb_in,
    const float* __restrict__ bprev, const float* __restrict__ Wn,
    const float* __restrict__ asn, const float* __restrict__ adn,
    unsigned short* __restrict__ hb_out,
    float* __restrict__ as_out, float* __restrict__ ad_out)
{
    int lane = threadIdx.x & 63;
    int half = lane >> 5;
    int hl = lane & 31;
    int node = (blockIdx.x * 256 + threadIdx.x) >> 5;  // 2 nodes per wave

    int beg = row[node], end = row[node + 1];
    float ad = ad_in[node];
    float acc0, acc1, den;
    {   // self loop
        float e = as_in[node] + ad;
        e = e > 0.f ? e : NEG_SLOPE * e;
        float w = __expf(e);
        ushort2 p = reinterpret_cast<const ushort2*>(hb_in)[(size_t)node * 32 + hl];
        acc0 = w * bf2f(p.x);
        acc1 = w * bf2f(p.y);
        den = w;
    }
    int mydeg = end - beg;
    int odeg = __shfl_xor(mydeg, 32, 64);
    int itmin = mydeg < odeg ? mydeg : odeg;
    int itmax = mydeg < odeg ? odeg : mydeg;
    int i = 0;
    for (; i + 2 <= itmin; i += 2) {
        int s0 = ssrc[beg + i], s1 = ssrc[beg + i + 1];
        edge_acc(s0, ad, hl, as_in, hb_in, acc0, acc1, den);
        edge_acc(s1, ad, hl, as_in, hb_in, acc0, acc1, den);
    }
    for (; i < itmax; ++i) {
        if (i < mydeg) {
            int s0 = ssrc[beg + i];
            edge_acc(s0, ad, hl, as_in, hb_in, acc0, acc1, den);
        }
    }
    float inv = 1.f / den;
    float2 bp = reinterpret_cast<const float2*>(bprev)[hl];
    float xe0 = fmaf(acc0, inv, bp.x);
    float xe1 = fmaf(acc1, inv, bp.y);
    xe0 = xe0 > 0.f ? xe0 : 0.f;
    xe1 = xe1 > 0.f ? xe1 : 0.f;

    // h_next[c] = sum_k xe[k] * Wn[k][c], xe spread over own half's 32 lanes
    float h0 = 0.f, h1 = 0.f;
    int base = half << 5;
    #pragma unroll
    for (int k2 = 0; k2 < 32; ++k2) {
        float a = __shfl(xe0, base + k2, 64);   // xe[2*k2]
        float b = __shfl(xe1, base + k2, 64);   // xe[2*k2+1]
        float2 w0 = reinterpret_cast<const float2*>(Wn)[(2 * k2) * 32 + hl];
        float2 w1 = reinterpret_cast<const float2*>(Wn)[(2 * k2 + 1) * 32 + hl];
        h0 = fmaf(a, w0.x, h0);
        h0 = fmaf(b, w1.x, h0);
        h1 = fmaf(a, w0.y, h1);
        h1 = fmaf(b, w1.y, h1);
    }
    ushort2 hp; hp.x = f2bf(h0); hp.y = f2bf(h1);
    reinterpret_cast<ushort2*>(hb_out)[(size_t)node * 32 + hl] = hp;

    float2 av = reinterpret_cast<const float2*>(asn)[hl];
    float2 dv = reinterpret_cast<const float2*>(adn)[hl];
    float sa = h0 * av.x + h1 * av.y;
    float sd = h0 * dv.x + h1 * dv.y;
    #pragma unroll
    for (int off = 16; off > 0; off >>= 1) {
        sa += __shfl_xor(sa, off, 64);
        sd += __shfl_xor(sd, off, 64);
    }
    if (hl == 0) { as_out[node] = sa; ad_out[node] = sd; }
}

// aggregate last layer, fused gate: h3 = agg + b2; gvals = h3.gate_w + gate_b
__global__ __launch_bounds__(256) void k_aggr_gate(
    const int* __restrict__ row, const int* __restrict__ ssrc,
    const float* __restrict__ as_in, const float* __restrict__ ad_in,
    const unsigned short* __restrict__ hb_in,
    const float* __restrict__ b2, const float* __restrict__ gate_w,
    const float* __restrict__ gate_b,
    float* __restrict__ h3out, float* __restrict__ gvals)
{
    int lane = threadIdx.x & 63;
    int hl = lane & 31;
    int node = (blockIdx.x * 256 + threadIdx.x) >> 5;

    int beg = row[node], end = row[node + 1];
    float ad = ad_in[node];
    float acc0, acc1, den;
    {
        float e = as_in[node] + ad;
        e = e > 0.f ? e : NEG_SLOPE * e;
        float w = __expf(e);
        ushort2 p = reinterpret_cast<const ushort2*>(hb_in)[(size_t)node * 32 + hl];
        acc0 = w * bf2f(p.x);
        acc1 = w * bf2f(p.y);
        den = w;
    }
    int mydeg = end - beg;
    int odeg = __shfl_xor(mydeg, 32, 64);
    int itmin = mydeg < odeg ? mydeg : odeg;
    int itmax = mydeg < odeg ? odeg : mydeg;
    int i = 0;
    for (; i + 2 <= itmin; i += 2) {
        int s0 = ssrc[beg + i], s1 = ssrc[beg + i + 1];
        edge_acc(s0, ad, hl, as_in, hb_in, acc0, acc1, den);
        edge_acc(s1, ad, hl, as_in, hb_in, acc0, acc1, den);
    }
    for (; i < itmax; ++i) {
        if (i < mydeg) {
            int s0 = ssrc[beg + i];
            edge_acc(s0, ad, hl, as_in, hb_in, acc0, acc1, den);
        }
    }
    float inv = 1.f / den;
    float2 bp = reinterpret_cast<const float2*>(b2)[hl];
    float h30 = fmaf(acc0, inv, bp.x);
    float h31 = fmaf(acc1, inv, bp.y);
    float2 hv; hv.x = h30; hv.y = h31;
    reinterpret_cast<float2*>(h3out)[(size_t)node * 32 + hl] = hv;
    float2 gw = reinterpret_cast<const float2*>(gate_w)[hl];
    float s = h30 * gw.x + h31 * gw.y;
    #pragma unroll
    for (int off = 16; off > 0; off >>= 1) s += __shfl_xor(s, off, 64);
    if (hl == 0) gvals[node] = s + gate_b[0];
}

__device__ __forceinline__ int lower_bound_batch(const int* __restrict__ batch, int val) {
    int lo = 0, hi = NN;
    while (lo < hi) { int mid = (lo + hi) >> 1; if (batch[mid] < val) lo = mid + 1; else hi = mid; }
    return lo;
}

// One block per graph: softmax-pool + fused final linear
__global__ __launch_bounds__(256) void k_pool(
    const float* __restrict__ h3, const float* __restrict__ gvals,
    const int* __restrict__ batch, const float* __restrict__ lin_w,
    const float* __restrict__ lin_b, float* __restrict__ out)
{
    __shared__ float red[256];
    __shared__ float pooled[HD];
    __shared__ float s_sumexp;
    int g = blockIdx.x;
    int tid = threadIdx.x;
    int start = lower_bound_batch(batch, g);
    int end   = lower_bound_batch(batch, g + 1);

    float local = 0.f;
    for (int n = start + tid; n < end; n += 256) local += __expf(gvals[n]);
    red[tid] = local;
    __syncthreads();
    #pragma unroll
    for (int s = 128; s > 0; s >>= 1) {
        if (tid < s) red[tid] += red[tid + s];
        __syncthreads();
    }
    if (tid == 0) s_sumexp = red[0];
    __syncthreads();
    float inv = 1.f / s_sumexp;

    int wid = tid >> 6, lane = tid & 63;
    float acc = 0.f;
    for (int n = start + wid; n < end; n += 4) {
        float c = __expf(gvals[n]) * inv;
        acc = fmaf(c, h3[(size_t)n * HD + lane], acc);
    }
    __syncthreads();
    red[tid] = acc;
    __syncthreads();
    if (tid < 64) pooled[tid] = red[tid] + red[tid + 64] + red[tid + 128] + red[tid + 192];
    __syncthreads();

    if (tid < 64) {
        float o = lin_b[tid];
        #pragma unroll 8
        for (int c = 0; c < HD; ++c) o = fmaf(pooled[c], lin_w[c * HD + tid], o);
        out[g * HD + tid] = o;
    }
}

extern "C" void kernel_launch(void* const* d_in, const int* in_sizes, int n_in,
                              void* d_out, int out_size, void* d_ws, size_t ws_size,
                              hipStream_t stream)
{
    const float* x     = (const float*)d_in[0];
    const int*  ei     = (const int*)d_in[1];
    const int*  batch  = (const int*)d_in[2];
    const float* W[3]  = {(const float*)d_in[3], (const float*)d_in[7],  (const float*)d_in[11]};
    const float* as[3] = {(const float*)d_in[4], (const float*)d_in[8],  (const float*)d_in[12]};
    const float* ad[3] = {(const float*)d_in[5], (const float*)d_in[9],  (const float*)d_in[13]};
    const float* bb[3] = {(const float*)d_in[6], (const float*)d_in[10], (const float*)d_in[14]};
    const float* gate_w = (const float*)d_in[15];
    const float* gate_b = (const float*)d_in[16];
    const float* lin_w  = (const float*)d_in[17];
    const float* lin_b  = (const float*)d_in[18];
    float* out = (float*)d_out;

    const int* esrc = ei;
    const int* edst = ei + NE;

    float* wsf = (float*)d_ws;
    size_t off = 0;
    float* h3buf = wsf + off; off += (size_t)NN * HD;
    float* asA   = wsf + off; off += NN;
    float* adA   = wsf + off; off += NN;
    float* asB   = wsf + off; off += NN;
    float* adB   = wsf + off; off += NN;
    float* gvals = wsf + off; off += NN;
    unsigned short* hbA = (unsigned short*)(wsf + off); off += (size_t)NN * HD / 2;
    unsigned short* hbB = (unsigned short*)(wsf + off); off += (size_t)NN * HD / 2;
    int* wsi = (int*)(wsf + off);
    size_t ioff = 0;
    int* deg    = wsi + ioff; ioff += NN;
    int* row    = wsi + ioff; ioff += NN + 1;
    int* cursor = wsi + ioff; ioff += NN;
    int* bsum   = wsi + ioff; ioff += NBLK;
    int* boff   = wsi + ioff; ioff += NBLK;
    int* ssrc   = wsi + ioff; ioff += NE;

    dim3 blk(256);
    const int nodeBlocks64 = NN / 4;     // wave per node (transform0)
    const int nodeBlocks32 = NN / 8;     // 2 nodes per wave (aggr)
    const int edgeBlocks   = (NE + 255) / 256;

    // ---- CSR build (real edges only) ----
    (void)hipMemsetAsync(deg, 0, NN * sizeof(int), stream);
    k_hist<<<edgeBlocks, blk, 0, stream>>>(edst, deg);
    k_bsum<<<NBLK, blk, 0, stream>>>(deg, bsum);
    k_scanb<<<1, 512, 0, stream>>>(bsum, boff);
    k_scan2<<<NBLK, blk, 0, stream>>>(deg, boff, row, cursor);
    k_scatter<<<edgeBlocks, blk, 0, stream>>>(esrc, edst, cursor, ssrc);

    // ---- layer 0 transform ----
    k_transform0<<<nodeBlocks64, blk, 0, stream>>>(x, W[0], as[0], ad[0],
                                                   hbA, asA, adA);
    // ---- layer 0 aggr + layer 1 transform ----
    k_aggr_ft<<<nodeBlocks32, blk, 0, stream>>>(row, ssrc, asA, adA, hbA,
                                                bb[0], W[1], as[1], ad[1],
                                                hbB, asB, adB);
    // ---- layer 1 aggr + layer 2 transform ----
    k_aggr_ft<<<nodeBlocks32, blk, 0, stream>>>(row, ssrc, asB, adB, hbB,
                                                bb[1], W[2], as[2], ad[2],
                                                hbA, asA, adA);
    // ---- layer 2 aggr + gate ----
    k_aggr_gate<<<nodeBlocks32, blk, 0, stream>>>(row, ssrc, asA, adA, hbA,
                                                  bb[2], gate_w, gate_b,
                                                  h3buf, gvals);
    // ---- pooling + final linear ----
    k_pool<<<NG, blk, 0, stream>>>(h3buf, gvals, batch, lin_w, lin_b, out);
}

// Round 7
// 426.956 us; speedup vs baseline: 4.0716x; 1.2811x over previous
//
#include <hip/hip_runtime.h>
#include <hip/hip_bf16.h>
#include <math.h>

#define NN 100000      // nodes
#define NE 1000000     // real edges (self-loops handled analytically)
#define HD 64          // hidden / feature dim
#define NG 128         // graphs
#define NEG_SLOPE 0.2f
#define NBLK 391       // ceil(NN/256)

__device__ __forceinline__ float bf2f(unsigned short u) {
    return __uint_as_float(((unsigned)u) << 16);
}
__device__ __forceinline__ unsigned short f2bf(float f) {
    __hip_bfloat16 h = __float2bfloat16(f);
    return *reinterpret_cast<unsigned short*>(&h);
}
__device__ __forceinline__ float lrelu_exp(float e) {
    e = e > 0.f ? e : NEG_SLOPE * e;
    return __expf(e);
}

// ---------------- CSR build (real edges only; deg memset to 0 outside) ----

__global__ __launch_bounds__(256) void k_hist(const int* __restrict__ edst,
                                              int* __restrict__ deg) {
    int e = blockIdx.x * 256 + threadIdx.x;
    if (e < NE) atomicAdd(&deg[edst[e]], 1);
}

__global__ __launch_bounds__(256) void k_bsum(const int* __restrict__ deg,
                                              int* __restrict__ bsum) {
    __shared__ int sm[256];
    int i = blockIdx.x * 256 + threadIdx.x;
    sm[threadIdx.x] = (i < NN) ? deg[i] : 0;
    __syncthreads();
    #pragma unroll
    for (int s = 128; s > 0; s >>= 1) {
        if (threadIdx.x < s) sm[threadIdx.x] += sm[threadIdx.x + s];
        __syncthreads();
    }
    if (threadIdx.x == 0) bsum[blockIdx.x] = sm[0];
}

__global__ __launch_bounds__(512) void k_scanb(const int* __restrict__ bsum,
                                               int* __restrict__ boff) {
    __shared__ int sm[512];
    int t = threadIdx.x;
    int v = (t < NBLK) ? bsum[t] : 0;
    sm[t] = v;
    __syncthreads();
    #pragma unroll
    for (int s = 1; s < 512; s <<= 1) {
        int add = (t >= s) ? sm[t - s] : 0;
        __syncthreads();
        sm[t] += add;
        __syncthreads();
    }
    if (t < NBLK) boff[t] = sm[t] - v;   // exclusive
}

__global__ __launch_bounds__(256) void k_scan2(const int* __restrict__ deg,
                                               const int* __restrict__ boff,
                                               int* __restrict__ row,
                                               int* __restrict__ cursor) {
    __shared__ int sm[256];
    int t = threadIdx.x, i = blockIdx.x * 256 + t;
    int v = (i < NN) ? deg[i] : 0;
    sm[t] = v;
    __syncthreads();
    #pragma unroll
    for (int s = 1; s < 256; s <<= 1) {
        int add = (t >= s) ? sm[t - s] : 0;
        __syncthreads();
        sm[t] += add;
        __syncthreads();
    }
    int excl = boff[blockIdx.x] + sm[t] - v;
    if (i < NN) { row[i] = excl; cursor[i] = excl; }
    if (i == NN - 1) row[NN] = excl + v;
}

__global__ __launch_bounds__(256) void k_scatter(const int* __restrict__ esrc,
                                                 const int* __restrict__ edst,
                                                 int* __restrict__ cursor,
                                                 int* __restrict__ ssrc) {
    int e = blockIdx.x * 256 + threadIdx.x;
    if (e >= NE) return;
    int s = esrc[e];
    int d = edst[e];
    int pos = atomicAdd(&cursor[d], 1);
    __builtin_nontemporal_store(s, &ssrc[pos]);
}

// ---------------- layer-0 transform (from fp32 x) ----------------
__global__ __launch_bounds__(256) void k_transform0(
    const float* __restrict__ inp, const float* __restrict__ W,
    const float* __restrict__ a_src, const float* __restrict__ a_dst,
    unsigned short* __restrict__ hb,
    float* __restrict__ alpha_s, float* __restrict__ alpha_d)
{
    __shared__ float sx[256];
    int node = (blockIdx.x * 256 + threadIdx.x) >> 6;
    int lane = threadIdx.x & 63;
    sx[threadIdx.x] = inp[(size_t)node * HD + lane];
    __syncthreads();
    const float* sxw = sx + (threadIdx.x & 192);
    float hj = 0.f;
    #pragma unroll
    for (int k4 = 0; k4 < 16; ++k4) {
        float4 xv = reinterpret_cast<const float4*>(sxw)[k4];
        int kb = k4 * 4;
        hj = fmaf(xv.x, W[(kb + 0) * HD + lane], hj);
        hj = fmaf(xv.y, W[(kb + 1) * HD + lane], hj);
        hj = fmaf(xv.z, W[(kb + 2) * HD + lane], hj);
        hj = fmaf(xv.w, W[(kb + 3) * HD + lane], hj);
    }
    hb[(size_t)node * HD + lane] = f2bf(hj);
    float s = hj * a_src[lane];
    float d = hj * a_dst[lane];
    #pragma unroll
    for (int off = 32; off > 0; off >>= 1) {
        s += __shfl_xor(s, off, 64);
        d += __shfl_xor(d, off, 64);
    }
    if (lane == 0) { alpha_s[node] = s; alpha_d[node] = d; }
}

// ------------- fused aggregate core: 1 node per wave, lane = channel -------
// Wave-uniform edge walk; 4-deep batched gathers for MLP.
// Returns normalized aggregation for this node's channel `lane` in acc,
// weight-sum in den.
__device__ __forceinline__ void aggr_core(
    int node, int lane,
    const int* __restrict__ row, const int* __restrict__ ssrc,
    const float* __restrict__ as_in, const float* __restrict__ ad_in,
    const unsigned short* __restrict__ hb_in,
    float& accN, float& denN)
{
    int beg = row[node], end = row[node + 1];
    float ad = ad_in[node];
    // self loop
    float w = lrelu_exp(as_in[node] + ad);
    float acc = w * bf2f(hb_in[(size_t)node * HD + lane]);
    float den = w;
    int i = beg;
    for (; i + 4 <= end; i += 4) {
        int s0 = __builtin_amdgcn_readfirstlane(ssrc[i]);
        int s1 = __builtin_amdgcn_readfirstlane(ssrc[i + 1]);
        int s2 = __builtin_amdgcn_readfirstlane(ssrc[i + 2]);
        int s3 = __builtin_amdgcn_readfirstlane(ssrc[i + 3]);
        float a0 = as_in[s0], a1 = as_in[s1], a2 = as_in[s2], a3 = as_in[s3];
        unsigned short u0 = hb_in[(size_t)s0 * HD + lane];
        unsigned short u1 = hb_in[(size_t)s1 * HD + lane];
        unsigned short u2 = hb_in[(size_t)s2 * HD + lane];
        unsigned short u3 = hb_in[(size_t)s3 * HD + lane];
        float w0 = lrelu_exp(a0 + ad), w1 = lrelu_exp(a1 + ad);
        float w2 = lrelu_exp(a2 + ad), w3 = lrelu_exp(a3 + ad);
        acc = fmaf(w0, bf2f(u0), acc);
        acc = fmaf(w1, bf2f(u1), acc);
        acc = fmaf(w2, bf2f(u2), acc);
        acc = fmaf(w3, bf2f(u3), acc);
        den += (w0 + w1) + (w2 + w3);
    }
    for (; i < end; ++i) {
        int s0 = __builtin_amdgcn_readfirstlane(ssrc[i]);
        float w0 = lrelu_exp(as_in[s0] + ad);
        acc = fmaf(w0, bf2f(hb_in[(size_t)s0 * HD + lane]), acc);
        den += w0;
    }
    accN = acc; denN = den;
}

// aggregate layer l + fused transform of layer l+1 (LDS float4 dot)
__global__ __launch_bounds__(256) void k_aggr_ft(
    const int* __restrict__ row, const int* __restrict__ ssrc,
    const float* __restrict__ as_in, const float* __restrict__ ad_in,
    const unsigned short* __restrict__ hb_in,
    const float* __restrict__ bprev, const float* __restrict__ Wn,
    const float* __restrict__ asn, const float* __restrict__ adn,
    unsigned short* __restrict__ hb_out,
    float* __restrict__ as_out, float* __restrict__ ad_out)
{
    __shared__ float sx[256];
    int wslot = __builtin_amdgcn_readfirstlane(threadIdx.x >> 6);
    int node = blockIdx.x * 4 + wslot;
    int lane = threadIdx.x & 63;

    float acc, den;
    aggr_core(node, lane, row, ssrc, as_in, ad_in, hb_in, acc, den);

    float xe = fmaf(acc, 1.f / den, bprev[lane]);
    xe = xe > 0.f ? xe : 0.f;
    sx[threadIdx.x] = xe;   // same-wave write/read: no barrier needed
    const float* sxw = sx + (threadIdx.x & 192);
    float hj = 0.f;
    #pragma unroll
    for (int k4 = 0; k4 < 16; ++k4) {
        float4 xv = reinterpret_cast<const float4*>(sxw)[k4];
        int kb = k4 * 4;
        hj = fmaf(xv.x, Wn[(kb + 0) * HD + lane], hj);
        hj = fmaf(xv.y, Wn[(kb + 1) * HD + lane], hj);
        hj = fmaf(xv.z, Wn[(kb + 2) * HD + lane], hj);
        hj = fmaf(xv.w, Wn[(kb + 3) * HD + lane], hj);
    }
    hb_out[(size_t)node * HD + lane] = f2bf(hj);
    float s = hj * asn[lane];
    float d = hj * adn[lane];
    #pragma unroll
    for (int off = 32; off > 0; off >>= 1) {
        s += __shfl_xor(s, off, 64);
        d += __shfl_xor(d, off, 64);
    }
    if (lane == 0) { as_out[node] = s; ad_out[node] = d; }
}

// aggregate last layer + fused gate
__global__ __launch_bounds__(256) void k_aggr_gate(
    const int* __restrict__ row, const int* __restrict__ ssrc,
    const float* __restrict__ as_in, const float* __restrict__ ad_in,
    const unsigned short* __restrict__ hb_in,
    const float* __restrict__ b2, const float* __restrict__ gate_w,
    const float* __restrict__ gate_b,
    float* __restrict__ h3out, float* __restrict__ gvals)
{
    int wslot = __builtin_amdgcn_readfirstlane(threadIdx.x >> 6);
    int node = blockIdx.x * 4 + wslot;
    int lane = threadIdx.x & 63;

    float acc, den;
    aggr_core(node, lane, row, ssrc, as_in, ad_in, hb_in, acc, den);

    float h3 = fmaf(acc, 1.f / den, b2[lane]);
    h3out[(size_t)node * HD + lane] = h3;
    float s = h3 * gate_w[lane];
    #pragma unroll
    for (int off = 32; off > 0; off >>= 1) s += __shfl_xor(s, off, 64);
    if (lane == 0) gvals[node] = s + gate_b[0];
}

__device__ __forceinline__ int lower_bound_batch(const int* __restrict__ batch, int val) {
    int lo = 0, hi = NN;
    while (lo < hi) { int mid = (lo + hi) >> 1; if (batch[mid] < val) lo = mid + 1; else hi = mid; }
    return lo;
}

// One block per graph: softmax-pool + fused final linear
__global__ __launch_bounds__(256) void k_pool(
    const float* __restrict__ h3, const float* __restrict__ gvals,
    const int* __restrict__ batch, const float* __restrict__ lin_w,
    const float* __restrict__ lin_b, float* __restrict__ out)
{
    __shared__ float red[256];
    __shared__ float pooled[HD];
    __shared__ float s_sumexp;
    int g = blockIdx.x;
    int tid = threadIdx.x;
    int start = lower_bound_batch(batch, g);
    int end   = lower_bound_batch(batch, g + 1);

    float local = 0.f;
    for (int n = start + tid; n < end; n += 256) local += __expf(gvals[n]);
    red[tid] = local;
    __syncthreads();
    #pragma unroll
    for (int s = 128; s > 0; s >>= 1) {
        if (tid < s) red[tid] += red[tid + s];
        __syncthreads();
    }
    if (tid == 0) s_sumexp = red[0];
    __syncthreads();
    float inv = 1.f / s_sumexp;

    int wid = tid >> 6, lane = tid & 63;
    float acc = 0.f;
    for (int n = start + wid; n < end; n += 4) {
        float c = __expf(gvals[n]) * inv;
        acc = fmaf(c, h3[(size_t)n * HD + lane], acc);
    }
    __syncthreads();
    red[tid] = acc;
    __syncthreads();
    if (tid < 64) pooled[tid] = red[tid] + red[tid + 64] + red[tid + 128] + red[tid + 192];
    __syncthreads();

    if (tid < 64) {
        float o = lin_b[tid];
        #pragma unroll 8
        for (int c = 0; c < HD; ++c) o = fmaf(pooled[c], lin_w[c * HD + tid], o);
        out[g * HD + tid] = o;
    }
}

extern "C" void kernel_launch(void* const* d_in, const int* in_sizes, int n_in,
                              void* d_out, int out_size, void* d_ws, size_t ws_size,
                              hipStream_t stream)
{
    const float* x     = (const float*)d_in[0];
    const int*  ei     = (const int*)d_in[1];
    const int*  batch  = (const int*)d_in[2];
    const float* W[3]  = {(const float*)d_in[3], (const float*)d_in[7],  (const float*)d_in[11]};
    const float* as[3] = {(const float*)d_in[4], (const float*)d_in[8],  (const float*)d_in[12]};
    const float* ad[3] = {(const float*)d_in[5], (const float*)d_in[9],  (const float*)d_in[13]};
    const float* bb[3] = {(const float*)d_in[6], (const float*)d_in[10], (const float*)d_in[14]};
    const float* gate_w = (const float*)d_in[15];
    const float* gate_b = (const float*)d_in[16];
    const float* lin_w  = (const float*)d_in[17];
    const float* lin_b  = (const float*)d_in[18];
    float* out = (float*)d_out;

    const int* esrc = ei;
    const int* edst = ei + NE;

    float* wsf = (float*)d_ws;
    size_t off = 0;
    float* h3buf = wsf + off; off += (size_t)NN * HD;
    float* asA   = wsf + off; off += NN;
    float* adA   = wsf + off; off += NN;
    float* asB   = wsf + off; off += NN;
    float* adB   = wsf + off; off += NN;
    float* gvals = wsf + off; off += NN;
    unsigned short* hbA = (unsigned short*)(wsf + off); off += (size_t)NN * HD / 2;
    unsigned short* hbB = (unsigned short*)(wsf + off); off += (size_t)NN * HD / 2;
    int* wsi = (int*)(wsf + off);
    size_t ioff = 0;
    int* deg    = wsi + ioff; ioff += NN;
    int* row    = wsi + ioff; ioff += NN + 1;
    int* cursor = wsi + ioff; ioff += NN;
    int* bsum   = wsi + ioff; ioff += NBLK;
    int* boff   = wsi + ioff; ioff += NBLK;
    int* ssrc   = wsi + ioff; ioff += NE;

    dim3 blk(256);
    const int nodeBlocks64 = NN / 4;     // wave per node
    const int edgeBlocks   = (NE + 255) / 256;

    // ---- CSR build (real edges only) ----
    (void)hipMemsetAsync(deg, 0, NN * sizeof(int), stream);
    k_hist<<<edgeBlocks, blk, 0, stream>>>(edst, deg);
    k_bsum<<<NBLK, blk, 0, stream>>>(deg, bsum);
    k_scanb<<<1, 512, 0, stream>>>(bsum, boff);
    k_scan2<<<NBLK, blk, 0, stream>>>(deg, boff, row, cursor);
    k_scatter<<<edgeBlocks, blk, 0, stream>>>(esrc, edst, cursor, ssrc);

    // ---- layer 0 transform ----
    k_transform0<<<nodeBlocks64, blk, 0, stream>>>(x, W[0], as[0], ad[0],
                                                   hbA, asA, adA);
    // ---- layer 0 aggr + layer 1 transform ----
    k_aggr_ft<<<nodeBlocks64, blk, 0, stream>>>(row, ssrc, asA, adA, hbA,
                                                bb[0], W[1], as[1], ad[1],
                                                hbB, asB, adB);
    // ---- layer 1 aggr + layer 2 transform ----
    k_aggr_ft<<<nodeBlocks64, blk, 0, stream>>>(row, ssrc, asB, adB, hbB,
                                                bb[1], W[2], as[2], ad[2],
                                                hbA, asA, adA);
    // ---- layer 2 aggr + gate ----
    k_aggr_gate<<<nodeBlocks64, blk, 0, stream>>>(row, ssrc, asA, adA, hbA,
                                                  bb[2], gate_w, gate_b,
                                                  h3buf, gvals);
    // ---- pooling + final linear ----
    k_pool<<<NG, blk, 0, stream>>>(h3buf, gvals, batch, lin_w, lin_b, out);
}